// Round 8
// baseline (154.480 us; speedup 1.0000x reference)
//
#include <hip/hip_runtime.h>
#include <hip/hip_bf16.h>
#include <stdint.h>

#define NTOK 8192
#define DIM  1024
#define RD   128
#define NEXP 64
#define TOPK 8
#define MAXT 4096
#define NHB  32    // histogram blocks (256 tokens each)
#define JMAX 16    // gemm j-range (capacity 2048 tokens/expert; actual ~1024)

// d_out element offsets (f32 elements): output | weights | idx
#define W_OFF (NTOK * RD)            // 1048576
#define I_OFF (W_OFF + NTOK * TOPK)  // 1114112

// ws byte offsets (total 35,914,752 B — same proven footprint)
#define CNT_OFF  0
#define LIST_OFF 1024
#define GC_OFF   (LIST_OFF + NEXP * MAXT * 4)   // 1,049,600
#define BO_OFF   (GC_OFF + NHB * NEXP * 4)      // 1,057,792
#define NT_OFF   2360320
#define XB_OFF   (NT_OFF + (size_t)NEXP * RD * DIM * 2)    // 19,137,536
// NT region (16 MB) time-shared: sp f64 [4][NTOK][NEXP] during score/topk
// (exactly 16,777,216 B), then nT bf16 (nt_cast runs AFTER topk_k).
// XB region (16 MB): xb bf16, written by score_k (fused x_cast).

using bh8 = __attribute__((ext_vector_type(8))) short;
using fx4 = __attribute__((ext_vector_type(4))) float;

__device__ inline unsigned short f2bf(float f) {
    union { __hip_bfloat16 h; unsigned short u; } v;
    v.h = __float2bfloat16(f);
    return v.u;
}

// ---------------------------------------------------------------------------
// Kernel 0: neurons [e][d][r] f32  ->  nT [e][r][d] bf16  (B^T for MFMA)
// Runs AFTER topk_k (its output overwrites the sp region).
// ---------------------------------------------------------------------------
__global__ __launch_bounds__(256) void nt_cast(const float* __restrict__ nr,
                                               __hip_bfloat16* __restrict__ nT) {
    int bx  = blockIdx.x;
    int e   = bx >> 5;
    int sub = bx & 31;
    int d0  = (sub >> 1) * 64;
    int r0  = (sub & 1) * 64;
    __shared__ float t[64][65];
    int tid = threadIdx.x;
    int dd  = tid >> 2;
    int rr4 = (tid & 3) * 16;
    const float* src = nr + ((size_t)e * DIM + d0 + dd) * RD + r0 + rr4;
    fx4 v[4];
    #pragma unroll
    for (int u = 0; u < 4; ++u) v[u] = ((const fx4*)src)[u];
    #pragma unroll
    for (int u = 0; u < 4; ++u)
        #pragma unroll
        for (int c = 0; c < 4; ++c) t[dd][rr4 + u * 4 + c] = v[u][c];
    __syncthreads();
    int rr  = tid >> 2;
    int dd4 = (tid & 3) * 16;
    union { unsigned short u[16]; uint4 q[2]; } o;
    #pragma unroll
    for (int i = 0; i < 16; ++i) o.u[i] = f2bf(t[dd4 + i][rr]);
    __hip_bfloat16* dst = nT + ((size_t)e * RD + r0 + rr) * DIM + d0 + dd4;
    ((uint4*)dst)[0] = o.q[0];
    ((uint4*)dst)[1] = o.q[1];
}

// ---------------------------------------------------------------------------
// Kernel 1: fp64 partial router scores, D-split x4 -> sp[ds][T][n]
// ALSO emits xb bf16 (fused x_cast): each block covers x[tb..tb+64) x 256 d
// exactly once across the grid.
// ---------------------------------------------------------------------------
__global__ __launch_bounds__(256) void score_k(const float* __restrict__ x,
                                               const float* __restrict__ rw,
                                               double* __restrict__ sp,
                                               unsigned short* __restrict__ xb) {
    __shared__ __align__(16) char smem[2 * 64 * 68 * 4];
    float (*Xs)[68] = (float (*)[68])smem;
    float (*Ws)[68] = (float (*)[68])(smem + 64 * 68 * 4);
    double (*Ssc)[65] = (double (*)[65])smem;

    int tid = threadIdx.x;
    int ds  = blockIdx.x & 3;
    int tb  = (blockIdx.x >> 2) * 64;
    int ni  = tid & 15;
    int ti  = tid >> 4;

    double acc[4][4];
    #pragma unroll
    for (int i = 0; i < 4; ++i)
        #pragma unroll
        for (int j = 0; j < 4; ++j) acc[i][j] = 0.0;

    int srow = tid >> 2;
    int scol = (tid & 3) * 16;

    for (int c = 0; c < 4; ++c) {
        int d0 = (ds * 4 + c) * 64;
        const float* xs = x  + (size_t)(tb + srow) * DIM + d0 + scol;
        const float* ws = rw + (size_t)srow        * DIM + d0 + scol;
        fx4 xv[4], wv[4];
        #pragma unroll
        for (int u = 0; u < 4; ++u) { xv[u] = ((const fx4*)xs)[u]; wv[u] = ((const fx4*)ws)[u]; }
        __syncthreads();
        #pragma unroll
        for (int u = 0; u < 4; ++u) {
            *(fx4*)&Xs[srow][scol + u * 4] = xv[u];
            *(fx4*)&Ws[srow][scol + u * 4] = wv[u];
        }
        // fused x_cast: this thread's 16 floats -> 16 bf16 (2 x 16 B stores)
        {
            bh8 o0, o1;
            #pragma unroll
            for (int c2 = 0; c2 < 4; ++c2) {
                o0[c2]     = (short)f2bf(xv[0][c2]);
                o0[4 + c2] = (short)f2bf(xv[1][c2]);
                o1[c2]     = (short)f2bf(xv[2][c2]);
                o1[4 + c2] = (short)f2bf(xv[3][c2]);
            }
            unsigned short* xd = xb + (size_t)(tb + srow) * DIM + d0 + scol;
            *(bh8*)xd = o0;
            *(bh8*)(xd + 8) = o1;
        }
        __syncthreads();
        for (int dq = 0; dq < 64; dq += 4) {
            fx4 xa[4], wb[4];
            #pragma unroll
            for (int i = 0; i < 4; ++i) xa[i] = *(const fx4*)&Xs[ti + 16 * i][dq];
            #pragma unroll
            for (int j = 0; j < 4; ++j) wb[j] = *(const fx4*)&Ws[ni + 16 * j][dq];
            #pragma unroll
            for (int i = 0; i < 4; ++i)
                #pragma unroll
                for (int j = 0; j < 4; ++j)
                    acc[i][j] += (double)xa[i][0] * (double)wb[j][0]
                               + (double)xa[i][1] * (double)wb[j][1]
                               + (double)xa[i][2] * (double)wb[j][2]
                               + (double)xa[i][3] * (double)wb[j][3];
        }
    }
    __syncthreads();
    #pragma unroll
    for (int i = 0; i < 4; ++i)
        #pragma unroll
        for (int j = 0; j < 4; ++j) Ssc[ti + 16 * i][ni + 16 * j] = acc[i][j];
    __syncthreads();

    int t  = tid >> 2;
    int n0 = (tid & 3) * 16;
    double* dst = sp + ((size_t)ds * NTOK + tb + t) * NEXP + n0;
    #pragma unroll
    for (int k = 0; k < 16; ++k) dst[k] = Ssc[t][n0 + k];
}

// ---------------------------------------------------------------------------
// Kernel 2: wave-per-token f64 top-8 + softmax. Plain stores only (NO atomics).
// ---------------------------------------------------------------------------
__global__ __launch_bounds__(256) void topk_k(const double* __restrict__ sp,
                                              float* __restrict__ out) {
    int wave = threadIdx.x >> 6, lane = threadIdx.x & 63;
    int T = blockIdx.x * 4 + wave;

    const double* base = sp + (size_t)T * NEXP + lane;
    const size_t SL = (size_t)NTOK * NEXP;
    double s = base[0] + base[SL] + base[2 * SL] + base[3 * SL];

    double vals[TOPK]; int idxs[TOPK];
    double cur = s;
    #pragma unroll
    for (int p = 0; p < TOPK; ++p) {
        double v = cur; int i = lane;
        #pragma unroll
        for (int off = 32; off > 0; off >>= 1) {
            double ov = __shfl_xor(v, off, 64);
            int    oi = __shfl_xor(i, off, 64);
            if (ov > v || (ov == v && oi < i)) { v = ov; i = oi; }
        }
        vals[p] = v; idxs[p] = i;
        if (lane == i) cur = -1e300;
    }

    double m = vals[0], sum = 0.0, ex[TOPK];
    #pragma unroll
    for (int p = 0; p < TOPK; ++p) { ex[p] = exp(vals[p] - m); sum += ex[p]; }
    double inv = 1.0 / sum;

    if (lane < TOPK) {
        int p = lane;
        out[W_OFF + T * TOPK + p] = (float)(ex[p] * inv);
        out[I_OFF + T * TOPK + p] = (float)idxs[p];
    }
}

// ---------------------------------------------------------------------------
// Kernel 3: per-block expert histogram (LDS atomics only)
// ---------------------------------------------------------------------------
__global__ __launch_bounds__(256) void hist_k(const float* __restrict__ out,
                                              int* __restrict__ gcnt) {
    __shared__ int lh[NEXP];
    int tid = threadIdx.x;
    if (tid < NEXP) lh[tid] = 0;
    __syncthreads();
    int T = blockIdx.x * 256 + tid;
    const fx4* ip = (const fx4*)(out + I_OFF + (size_t)T * TOPK);
    fx4 a = ip[0], b = ip[1];
    #pragma unroll
    for (int p = 0; p < 4; ++p) { atomicAdd(&lh[(int)a[p]], 1); atomicAdd(&lh[(int)b[p]], 1); }
    __syncthreads();
    if (tid < NEXP) gcnt[blockIdx.x * NEXP + tid] = lh[tid];
}

// ---------------------------------------------------------------------------
// Kernel 4: scan block counts -> per-block bases + total cnt
// ---------------------------------------------------------------------------
__global__ __launch_bounds__(64) void scan_k(const int* __restrict__ gcnt,
                                             int* __restrict__ boff,
                                             int* __restrict__ cnt) {
    int e = threadIdx.x;   // 64 lanes
    int s = 0;
    #pragma unroll
    for (int b = 0; b < NHB; ++b) {
        boff[b * NEXP + e] = e * MAXT + s;
        s += gcnt[b * NEXP + e];
    }
    cnt[e] = s;
}

// ---------------------------------------------------------------------------
// Kernel 5: scatter entries into lists (LDS-atomic local ranks)
// ---------------------------------------------------------------------------
__global__ __launch_bounds__(256) void scatter_k(const float* __restrict__ out,
                                                 const int* __restrict__ boff,
                                                 int* __restrict__ lists) {
    __shared__ int lh[NEXP];
    __shared__ int bo[NEXP];
    int tid = threadIdx.x;
    if (tid < NEXP) { lh[tid] = 0; bo[tid] = boff[blockIdx.x * NEXP + tid]; }
    __syncthreads();
    int T = blockIdx.x * 256 + tid;
    const fx4* ip = (const fx4*)(out + I_OFF + (size_t)T * TOPK);
    fx4 a = ip[0], b = ip[1];
    int ev[TOPK] = {(int)a[0], (int)a[1], (int)a[2], (int)a[3],
                    (int)b[0], (int)b[1], (int)b[2], (int)b[3]};
    #pragma unroll
    for (int p = 0; p < TOPK; ++p) {
        int e = ev[p];
        int pos = atomicAdd(&lh[e], 1);
        lists[bo[e] + pos] = (T << 3) | p;
    }
}

// ---------------------------------------------------------------------------
// Kernel 6: grouped gather-GEMM, tile 128 tok x 128 R, BK=64, DEPTH-4
// pipeline: 4 LDS buffers (128 KB), 3 tiles in flight, steady-state wait
// vmcnt(16) (= 2 newer tiles x 8 loads stay outstanding) -> stall/iter ~ L/3.
// Per iter: wait vmcnt -> barrier -> MFMA -> lgkmcnt(0) -> barrier ->
// stage(kt+3). vmcnt never drains to 0 until the last tile (T3+T4, m218).
// ---------------------------------------------------------------------------
__global__ __launch_bounds__(256) void gemm_k(const unsigned short* __restrict__ xb,
                                              const unsigned short* __restrict__ nTb,
                                              const int* __restrict__ cnt,
                                              const int* __restrict__ lists,
                                              float* __restrict__ outf) {
    int e = blockIdx.x & 63;
    int j = blockIdx.x >> 6;       // 0..JMAX-1
    int ce = cnt[e];
    int base = j * 128;
    if (base >= ce) return;

    __shared__ unsigned short As[4][128 * 64];   // 64 KB
    __shared__ unsigned short Bs[4][128 * 64];   // 64 KB
    __shared__ int   plist[128];
    __shared__ float wl[128];

    int tid = threadIdx.x;
    int wave = tid >> 6, lane = tid & 63;
    if (tid < 128) {
        int idx = base + tid;
        int p = (idx < ce) ? lists[e * MAXT + idx] : -1;
        plist[tid] = p;
        wl[tid] = (p >= 0) ? outf[W_OFF + p] : 0.0f;
    }
    __syncthreads();

    fx4 acc[4][4];
    #pragma unroll
    for (int a = 0; a < 4; ++a)
        #pragma unroll
        for (int b = 0; b < 4; ++b) acc[a][b] = (fx4){0.f, 0.f, 0.f, 0.f};

    unsigned soff = 16u * (unsigned)((lane & 7) ^ (lane >> 3));
    const char* asrc[4];
    const char* bsrc[4];
    const char* xbb = (const char*)xb;
    const char* ntb = (const char*)(nTb + (size_t)e * RD * DIM);
    #pragma unroll
    for (int c = 0; c < 4; ++c) {
        int row = (wave * 4 + c) * 8 + (lane >> 3);
        int p = plist[row];
        int tok = (p < 0) ? 0 : (p >> 3);
        asrc[c] = xbb + (size_t)tok * (DIM * 2) + soff;
        bsrc[c] = ntb + (size_t)row * (DIM * 2) + soff;
    }

    int wm = (wave >> 1) * 64, wn = (wave & 1) * 64;
    int lr = lane & 15, lk = (lane >> 4) * 8;
    int lg = lane >> 4;

    auto stage = [&](int kt, int bsel) {
        int db = kt * 128;
        #pragma unroll
        for (int c = 0; c < 4; ++c) {
            __builtin_amdgcn_global_load_lds(
                (const __attribute__((address_space(1))) void*)(asrc[c] + db),
                (__attribute__((address_space(3))) void*)(&As[bsel][(wave * 4 + c) * 512]),
                16, 0, 0);
        }
        #pragma unroll
        for (int c = 0; c < 4; ++c) {
            __builtin_amdgcn_global_load_lds(
                (const __attribute__((address_space(1))) void*)(bsrc[c] + db),
                (__attribute__((address_space(3))) void*)(&Bs[bsel][(wave * 4 + c) * 512]),
                16, 0, 0);
        }
    };

    auto mfma_tile = [&](int bsel) {
        const char* Ab = (const char*)As[bsel];
        const char* Bb = (const char*)Bs[bsel];
        #pragma unroll
        for (int kk = 0; kk < 2; ++kk) {
            int k0 = kk * 32;
            bh8 av[4], bv[4];
            #pragma unroll
            for (int mf = 0; mf < 4; ++mf) {
                unsigned row = (unsigned)(wm + mf * 16 + lr);
                unsigned bo = row * 128 + (unsigned)(k0 + lk) * 2;
                bo ^= (row & 7) << 4;
                av[mf] = *(const bh8*)(Ab + bo);
            }
            #pragma unroll
            for (int nf = 0; nf < 4; ++nf) {
                unsigned row = (unsigned)(wn + nf * 16 + lr);
                unsigned bo = row * 128 + (unsigned)(k0 + lk) * 2;
                bo ^= (row & 7) << 4;
                bv[nf] = *(const bh8*)(Bb + bo);
            }
            #pragma unroll
            for (int mf = 0; mf < 4; ++mf)
                #pragma unroll
                for (int nf = 0; nf < 4; ++nf)
                    acc[mf][nf] = __builtin_amdgcn_mfma_f32_16x16x32_bf16(av[mf], bv[nf], acc[mf][nf], 0, 0, 0);
        }
    };

    // prologue: 3 tiles in flight (24 loads/lane)
    stage(0, 0);
    stage(1, 1);
    stage(2, 2);

    for (int kt = 0; kt < 14; ++kt) {
        // oldest 8 loads (tile kt) done; 2 newer tiles (16 loads) stay in flight
        asm volatile("s_waitcnt vmcnt(16)" ::: "memory");
        __builtin_amdgcn_s_barrier();
        asm volatile("" ::: "memory");
        mfma_tile(kt & 3);
        asm volatile("s_waitcnt lgkmcnt(0)" ::: "memory");
        __builtin_amdgcn_s_barrier();
        asm volatile("" ::: "memory");
        if (kt < 13) stage(kt + 3, (kt + 3) & 3);
    }
    // kt = 14: tiles 14,15 outstanding -> wait tile 14 (leave 8)
    asm volatile("s_waitcnt vmcnt(8)" ::: "memory");
    __builtin_amdgcn_s_barrier();
    asm volatile("" ::: "memory");
    mfma_tile(14 & 3);
    // kt = 15: drain
    asm volatile("s_waitcnt vmcnt(0)" ::: "memory");
    __builtin_amdgcn_s_barrier();
    asm volatile("" ::: "memory");
    mfma_tile(15 & 3);

    #pragma unroll
    for (int mf = 0; mf < 4; ++mf) {
        #pragma unroll
        for (int rg = 0; rg < 4; ++rg) {
            int row = wm + mf * 16 + lg * 4 + rg;
            int p = plist[row];
            if (p < 0) continue;
            float wg = wl[row];
            int t = p >> 3;
            #pragma unroll
            for (int nf = 0; nf < 4; ++nf) {
                int r = wn + nf * 16 + lr;
                atomicAdd(&outf[(size_t)t * RD + r], acc[mf][nf][rg] * wg);
            }
        }
    }
}

// ---------------------------------------------------------------------------
extern "C" void kernel_launch(void* const* d_in, const int* in_sizes, int n_in,
                              void* d_out, int out_size, void* d_ws, size_t ws_size,
                              hipStream_t stream) {
    const float* x  = (const float*)d_in[0];
    const float* rw = (const float*)d_in[1];
    const float* nr = (const float*)d_in[2];
    float* out = (float*)d_out;
    char* ws = (char*)d_ws;
    int*    cnt   = (int*)(ws + CNT_OFF);
    int*    lists = (int*)(ws + LIST_OFF);
    int*    gcnt  = (int*)(ws + GC_OFF);
    int*    boff  = (int*)(ws + BO_OFF);
    __hip_bfloat16* nT = (__hip_bfloat16*)(ws + NT_OFF);
    double* sp    = (double*)(ws + NT_OFF);          // sp lives in NT region...
    unsigned short* xbu = (unsigned short*)(ws + XB_OFF);

    hipMemsetAsync(out, 0, (size_t)NTOK * RD * sizeof(float), stream);
    score_k<<<512, 256, 0, stream>>>(x, rw, sp, xbu);   // also emits xb (fused x_cast)
    topk_k<<<NTOK / 4, 256, 0, stream>>>(sp, out);
    nt_cast<<<2048, 256, 0, stream>>>(nr, nT);          // ...then nT overwrites sp
    hist_k<<<NHB, 256, 0, stream>>>(out, gcnt);
    scan_k<<<1, 64, 0, stream>>>(gcnt, boff, cnt);
    scatter_k<<<NHB, 256, 0, stream>>>(out, boff, lists);
    gemm_k<<<NEXP * JMAX, 256, 0, stream>>>(xbu, (const unsigned short*)nT, cnt, lists, out);
}

// Round 9
// 122.509 us; speedup vs baseline: 1.2610x; 1.2610x over previous
//
#include <hip/hip_runtime.h>
#include <hip/hip_bf16.h>
#include <stdint.h>

#define NTOK 8192
#define DIM  1024
#define RD   128
#define NEXP 64
#define TOPK 8
#define MAXT 4096
#define NHB  32    // histogram blocks (256 tokens each)
#define JMAX 16    // gemm j-range (covers 2048 tokens/expert; actual ~1024±150)

// d_out element offsets (f32 elements): output | weights | idx
#define W_OFF (NTOK * RD)            // 1048576
#define I_OFF (W_OFF + NTOK * TOPK)  // 1114112

// ws byte offsets
#define CNT_OFF  0
#define LIST_OFF 1024
#define GC_OFF   (LIST_OFF + NEXP * MAXT * 4)   // 1,049,600
#define BO_OFF   (GC_OFF + NHB * NEXP * 4)      // 1,057,792
#define NT_OFF   2360320
#define XB_OFF   (NT_OFF + (size_t)NEXP * RD * DIM * 2)    // 19,137,536
#define PW_OFF   (XB_OFF + (size_t)NTOK * DIM * 2)         // 35,914,752
#define PW_END   (PW_OFF + (size_t)NTOK * TOPK * RD * 2)   // 52,691,968
// NT region (16 MB) time-shared: sp f64 [4][NTOK][NEXP] during score/topk,
// then nT bf16 (nt_cast runs AFTER topk_k). XB: xb bf16 (fused x_cast).
// PW region (16 MB, bf16 partials) used ONLY if ws_size >= PW_END.

using bh8 = __attribute__((ext_vector_type(8))) short;
using fx4 = __attribute__((ext_vector_type(4))) float;

__device__ inline unsigned short f2bf(float f) {
    union { __hip_bfloat16 h; unsigned short u; } v;
    v.h = __float2bfloat16(f);
    return v.u;
}

// ---------------------------------------------------------------------------
// Kernel 0: neurons [e][d][r] f32  ->  nT [e][r][d] bf16  (B^T for MFMA)
// ---------------------------------------------------------------------------
__global__ __launch_bounds__(256) void nt_cast(const float* __restrict__ nr,
                                               __hip_bfloat16* __restrict__ nT) {
    int bx  = blockIdx.x;
    int e   = bx >> 5;
    int sub = bx & 31;
    int d0  = (sub >> 1) * 64;
    int r0  = (sub & 1) * 64;
    __shared__ float t[64][65];
    int tid = threadIdx.x;
    int dd  = tid >> 2;
    int rr4 = (tid & 3) * 16;
    const float* src = nr + ((size_t)e * DIM + d0 + dd) * RD + r0 + rr4;
    fx4 v[4];
    #pragma unroll
    for (int u = 0; u < 4; ++u) v[u] = ((const fx4*)src)[u];
    #pragma unroll
    for (int u = 0; u < 4; ++u)
        #pragma unroll
        for (int c = 0; c < 4; ++c) t[dd][rr4 + u * 4 + c] = v[u][c];
    __syncthreads();
    int rr  = tid >> 2;
    int dd4 = (tid & 3) * 16;
    union { unsigned short u[16]; uint4 q[2]; } o;
    #pragma unroll
    for (int i = 0; i < 16; ++i) o.u[i] = f2bf(t[dd4 + i][rr]);
    __hip_bfloat16* dst = nT + ((size_t)e * RD + r0 + rr) * DIM + d0 + dd4;
    ((uint4*)dst)[0] = o.q[0];
    ((uint4*)dst)[1] = o.q[1];
}

// ---------------------------------------------------------------------------
// Kernel 1: fp64 partial router scores, D-split x4 -> sp[ds][T][n]
// ALSO emits xb bf16 (fused x_cast).
// ---------------------------------------------------------------------------
__global__ __launch_bounds__(256) void score_k(const float* __restrict__ x,
                                               const float* __restrict__ rw,
                                               double* __restrict__ sp,
                                               unsigned short* __restrict__ xb) {
    __shared__ __align__(16) char smem[2 * 64 * 68 * 4];
    float (*Xs)[68] = (float (*)[68])smem;
    float (*Ws)[68] = (float (*)[68])(smem + 64 * 68 * 4);
    double (*Ssc)[65] = (double (*)[65])smem;

    int tid = threadIdx.x;
    int ds  = blockIdx.x & 3;
    int tb  = (blockIdx.x >> 2) * 64;
    int ni  = tid & 15;
    int ti  = tid >> 4;

    double acc[4][4];
    #pragma unroll
    for (int i = 0; i < 4; ++i)
        #pragma unroll
        for (int j = 0; j < 4; ++j) acc[i][j] = 0.0;

    int srow = tid >> 2;
    int scol = (tid & 3) * 16;

    for (int c = 0; c < 4; ++c) {
        int d0 = (ds * 4 + c) * 64;
        const float* xs = x  + (size_t)(tb + srow) * DIM + d0 + scol;
        const float* ws = rw + (size_t)srow        * DIM + d0 + scol;
        fx4 xv[4], wv[4];
        #pragma unroll
        for (int u = 0; u < 4; ++u) { xv[u] = ((const fx4*)xs)[u]; wv[u] = ((const fx4*)ws)[u]; }
        __syncthreads();
        #pragma unroll
        for (int u = 0; u < 4; ++u) {
            *(fx4*)&Xs[srow][scol + u * 4] = xv[u];
            *(fx4*)&Ws[srow][scol + u * 4] = wv[u];
        }
        // fused x_cast
        {
            bh8 o0, o1;
            #pragma unroll
            for (int c2 = 0; c2 < 4; ++c2) {
                o0[c2]     = (short)f2bf(xv[0][c2]);
                o0[4 + c2] = (short)f2bf(xv[1][c2]);
                o1[c2]     = (short)f2bf(xv[2][c2]);
                o1[4 + c2] = (short)f2bf(xv[3][c2]);
            }
            unsigned short* xd = xb + (size_t)(tb + srow) * DIM + d0 + scol;
            *(bh8*)xd = o0;
            *(bh8*)(xd + 8) = o1;
        }
        __syncthreads();
        for (int dq = 0; dq < 64; dq += 4) {
            fx4 xa[4], wb[4];
            #pragma unroll
            for (int i = 0; i < 4; ++i) xa[i] = *(const fx4*)&Xs[ti + 16 * i][dq];
            #pragma unroll
            for (int j = 0; j < 4; ++j) wb[j] = *(const fx4*)&Ws[ni + 16 * j][dq];
            #pragma unroll
            for (int i = 0; i < 4; ++i)
                #pragma unroll
                for (int j = 0; j < 4; ++j)
                    acc[i][j] += (double)xa[i][0] * (double)wb[j][0]
                               + (double)xa[i][1] * (double)wb[j][1]
                               + (double)xa[i][2] * (double)wb[j][2]
                               + (double)xa[i][3] * (double)wb[j][3];
        }
    }
    __syncthreads();
    #pragma unroll
    for (int i = 0; i < 4; ++i)
        #pragma unroll
        for (int j = 0; j < 4; ++j) Ssc[ti + 16 * i][ni + 16 * j] = acc[i][j];
    __syncthreads();

    int t  = tid >> 2;
    int n0 = (tid & 3) * 16;
    double* dst = sp + ((size_t)ds * NTOK + tb + t) * NEXP + n0;
    #pragma unroll
    for (int k = 0; k < 16; ++k) dst[k] = Ssc[t][n0 + k];
}

// ---------------------------------------------------------------------------
// Kernel 2: wave-per-token f64 top-8 + softmax. Plain stores only.
// ---------------------------------------------------------------------------
__global__ __launch_bounds__(256) void topk_k(const double* __restrict__ sp,
                                              float* __restrict__ out) {
    int wave = threadIdx.x >> 6, lane = threadIdx.x & 63;
    int T = blockIdx.x * 4 + wave;

    const double* base = sp + (size_t)T * NEXP + lane;
    const size_t SL = (size_t)NTOK * NEXP;
    double s = base[0] + base[SL] + base[2 * SL] + base[3 * SL];

    double vals[TOPK]; int idxs[TOPK];
    double cur = s;
    #pragma unroll
    for (int p = 0; p < TOPK; ++p) {
        double v = cur; int i = lane;
        #pragma unroll
        for (int off = 32; off > 0; off >>= 1) {
            double ov = __shfl_xor(v, off, 64);
            int    oi = __shfl_xor(i, off, 64);
            if (ov > v || (ov == v && oi < i)) { v = ov; i = oi; }
        }
        vals[p] = v; idxs[p] = i;
        if (lane == i) cur = -1e300;
    }

    double m = vals[0], sum = 0.0, ex[TOPK];
    #pragma unroll
    for (int p = 0; p < TOPK; ++p) { ex[p] = exp(vals[p] - m); sum += ex[p]; }
    double inv = 1.0 / sum;

    if (lane < TOPK) {
        int p = lane;
        out[W_OFF + T * TOPK + p] = (float)(ex[p] * inv);
        out[I_OFF + T * TOPK + p] = (float)idxs[p];
    }
}

// ---------------------------------------------------------------------------
// Kernel 3: per-block expert histogram (LDS atomics only)
// ---------------------------------------------------------------------------
__global__ __launch_bounds__(256) void hist_k(const float* __restrict__ out,
                                              int* __restrict__ gcnt) {
    __shared__ int lh[NEXP];
    int tid = threadIdx.x;
    if (tid < NEXP) lh[tid] = 0;
    __syncthreads();
    int T = blockIdx.x * 256 + tid;
    const fx4* ip = (const fx4*)(out + I_OFF + (size_t)T * TOPK);
    fx4 a = ip[0], b = ip[1];
    #pragma unroll
    for (int p = 0; p < 4; ++p) { atomicAdd(&lh[(int)a[p]], 1); atomicAdd(&lh[(int)b[p]], 1); }
    __syncthreads();
    if (tid < NEXP) gcnt[blockIdx.x * NEXP + tid] = lh[tid];
}

// ---------------------------------------------------------------------------
// Kernel 4: scan block counts -> per-block bases + total cnt
// ---------------------------------------------------------------------------
__global__ __launch_bounds__(64) void scan_k(const int* __restrict__ gcnt,
                                             int* __restrict__ boff,
                                             int* __restrict__ cnt) {
    int e = threadIdx.x;
    int s = 0;
    #pragma unroll
    for (int b = 0; b < NHB; ++b) {
        boff[b * NEXP + e] = e * MAXT + s;
        s += gcnt[b * NEXP + e];
    }
    cnt[e] = s;
}

// ---------------------------------------------------------------------------
// Kernel 5: scatter entries into lists (LDS-atomic local ranks)
// ---------------------------------------------------------------------------
__global__ __launch_bounds__(256) void scatter_k(const float* __restrict__ out,
                                                 const int* __restrict__ boff,
                                                 int* __restrict__ lists) {
    __shared__ int lh[NEXP];
    __shared__ int bo[NEXP];
    int tid = threadIdx.x;
    if (tid < NEXP) { lh[tid] = 0; bo[tid] = boff[blockIdx.x * NEXP + tid]; }
    __syncthreads();
    int T = blockIdx.x * 256 + tid;
    const fx4* ip = (const fx4*)(out + I_OFF + (size_t)T * TOPK);
    fx4 a = ip[0], b = ip[1];
    int ev[TOPK] = {(int)a[0], (int)a[1], (int)a[2], (int)a[3],
                    (int)b[0], (int)b[1], (int)b[2], (int)b[3]};
    #pragma unroll
    for (int p = 0; p < TOPK; ++p) {
        int e = ev[p];
        int pos = atomicAdd(&lh[e], 1);
        lists[bo[e] + pos] = (T << 3) | p;
    }
}

// ---------------------------------------------------------------------------
// Kernel 6: grouped gather-GEMM, 128 tok x 128 R, BK=64, depth-2 counted-vmcnt
// pipeline (r7 structure, best known). Epilogue: if use_pw, plain bf16 stores
// of weighted partials to pw[p][r] (no atomics); else f32 atomicAdd into out.
// ---------------------------------------------------------------------------
__global__ __launch_bounds__(256) void gemm_k(const unsigned short* __restrict__ xb,
                                              const unsigned short* __restrict__ nTb,
                                              const int* __restrict__ cnt,
                                              const int* __restrict__ lists,
                                              float* __restrict__ outf,
                                              unsigned short* __restrict__ pw,
                                              int use_pw) {
    int e = blockIdx.x & 63;
    int j = blockIdx.x >> 6;
    int ce = cnt[e];
    int base = j * 128;
    if (base >= ce) return;

    __shared__ unsigned short As[2][128 * 64];
    __shared__ unsigned short Bs[2][128 * 64];
    __shared__ int   plist[128];
    __shared__ float wl[128];

    int tid = threadIdx.x;
    int wave = tid >> 6, lane = tid & 63;
    if (tid < 128) {
        int idx = base + tid;
        int p = (idx < ce) ? lists[e * MAXT + idx] : -1;
        plist[tid] = p;
        wl[tid] = (p >= 0) ? outf[W_OFF + p] : 0.0f;
    }
    __syncthreads();

    fx4 acc[4][4];
    #pragma unroll
    for (int a = 0; a < 4; ++a)
        #pragma unroll
        for (int b = 0; b < 4; ++b) acc[a][b] = (fx4){0.f, 0.f, 0.f, 0.f};

    unsigned soff = 16u * (unsigned)((lane & 7) ^ (lane >> 3));
    const char* asrc[4];
    const char* bsrc[4];
    const char* xbb = (const char*)xb;
    const char* ntb = (const char*)(nTb + (size_t)e * RD * DIM);
    #pragma unroll
    for (int c = 0; c < 4; ++c) {
        int row = (wave * 4 + c) * 8 + (lane >> 3);
        int p = plist[row];
        int tok = (p < 0) ? 0 : (p >> 3);
        asrc[c] = xbb + (size_t)tok * (DIM * 2) + soff;
        bsrc[c] = ntb + (size_t)row * (DIM * 2) + soff;
    }

    int wm = (wave >> 1) * 64, wn = (wave & 1) * 64;
    int lr = lane & 15, lk = (lane >> 4) * 8;
    int lg = lane >> 4;

    auto stage = [&](int kt, int bsel) {
        int db = kt * 128;
        #pragma unroll
        for (int c = 0; c < 4; ++c) {
            __builtin_amdgcn_global_load_lds(
                (const __attribute__((address_space(1))) void*)(asrc[c] + db),
                (__attribute__((address_space(3))) void*)(&As[bsel][(wave * 4 + c) * 512]),
                16, 0, 0);
        }
        #pragma unroll
        for (int c = 0; c < 4; ++c) {
            __builtin_amdgcn_global_load_lds(
                (const __attribute__((address_space(1))) void*)(bsrc[c] + db),
                (__attribute__((address_space(3))) void*)(&Bs[bsel][(wave * 4 + c) * 512]),
                16, 0, 0);
        }
    };

    auto mfma_tile = [&](int bsel) {
        const char* Ab = (const char*)As[bsel];
        const char* Bb = (const char*)Bs[bsel];
        #pragma unroll
        for (int kk = 0; kk < 2; ++kk) {
            int k0 = kk * 32;
            bh8 av[4], bv[4];
            #pragma unroll
            for (int mf = 0; mf < 4; ++mf) {
                unsigned row = (unsigned)(wm + mf * 16 + lr);
                unsigned bo = row * 128 + (unsigned)(k0 + lk) * 2;
                bo ^= (row & 7) << 4;
                av[mf] = *(const bh8*)(Ab + bo);
            }
            #pragma unroll
            for (int nf = 0; nf < 4; ++nf) {
                unsigned row = (unsigned)(wn + nf * 16 + lr);
                unsigned bo = row * 128 + (unsigned)(k0 + lk) * 2;
                bo ^= (row & 7) << 4;
                bv[nf] = *(const bh8*)(Bb + bo);
            }
            #pragma unroll
            for (int mf = 0; mf < 4; ++mf)
                #pragma unroll
                for (int nf = 0; nf < 4; ++nf)
                    acc[mf][nf] = __builtin_amdgcn_mfma_f32_16x16x32_bf16(av[mf], bv[nf], acc[mf][nf], 0, 0, 0);
        }
    };

    // prologue: 2 tiles in flight (16 loads/lane)
    stage(0, 0);
    stage(1, 1);

    for (int kt = 0; kt < 15; ++kt) {
        int bsel = kt & 1;
        asm volatile("s_waitcnt vmcnt(8)" ::: "memory");
        __builtin_amdgcn_s_barrier();
        asm volatile("" ::: "memory");
        mfma_tile(bsel);
        asm volatile("s_waitcnt lgkmcnt(0)" ::: "memory");
        __builtin_amdgcn_s_barrier();
        asm volatile("" ::: "memory");
        if (kt < 14) stage(kt + 2, bsel);
    }
    asm volatile("s_waitcnt vmcnt(0)" ::: "memory");
    __builtin_amdgcn_s_barrier();
    asm volatile("" ::: "memory");
    mfma_tile(1);

    if (use_pw) {
        #pragma unroll
        for (int mf = 0; mf < 4; ++mf) {
            #pragma unroll
            for (int rg = 0; rg < 4; ++rg) {
                int row = wm + mf * 16 + lg * 4 + rg;
                int p = plist[row];
                if (p < 0) continue;
                float wg = wl[row];
                #pragma unroll
                for (int nf = 0; nf < 4; ++nf) {
                    int r = wn + nf * 16 + lr;
                    pw[(size_t)p * RD + r] = f2bf(acc[mf][nf][rg] * wg);
                }
            }
        }
    } else {
        #pragma unroll
        for (int mf = 0; mf < 4; ++mf) {
            #pragma unroll
            for (int rg = 0; rg < 4; ++rg) {
                int row = wm + mf * 16 + lg * 4 + rg;
                int p = plist[row];
                if (p < 0) continue;
                float wg = wl[row];
                int t = p >> 3;
                #pragma unroll
                for (int nf = 0; nf < 4; ++nf) {
                    int r = wn + nf * 16 + lr;
                    atomicAdd(&outf[(size_t)t * RD + r], acc[mf][nf][rg] * wg);
                }
            }
        }
    }
}

// ---------------------------------------------------------------------------
// Kernel 7: y[t][r] = sum_k pw[(t*8+k)][r]   (pw path only; coalesced)
// ---------------------------------------------------------------------------
__global__ __launch_bounds__(256) void reduce_k(const unsigned short* __restrict__ pw,
                                                float* __restrict__ y) {
    int gid = blockIdx.x * 256 + threadIdx.x;
    int t = gid >> 7, r = gid & 127;
    float s = 0.f;
    #pragma unroll
    for (int k = 0; k < TOPK; ++k) {
        union { unsigned short u; } b;
        b.u = pw[((size_t)t * TOPK + k) * RD + r];
        unsigned int w = ((unsigned int)b.u) << 16;
        s += __uint_as_float(w);
    }
    y[gid] = s;
}

// ---------------------------------------------------------------------------
extern "C" void kernel_launch(void* const* d_in, const int* in_sizes, int n_in,
                              void* d_out, int out_size, void* d_ws, size_t ws_size,
                              hipStream_t stream) {
    const float* x  = (const float*)d_in[0];
    const float* rw = (const float*)d_in[1];
    const float* nr = (const float*)d_in[2];
    float* out = (float*)d_out;
    char* ws = (char*)d_ws;
    int*    cnt   = (int*)(ws + CNT_OFF);
    int*    lists = (int*)(ws + LIST_OFF);
    int*    gcnt  = (int*)(ws + GC_OFF);
    int*    boff  = (int*)(ws + BO_OFF);
    __hip_bfloat16* nT = (__hip_bfloat16*)(ws + NT_OFF);
    double* sp    = (double*)(ws + NT_OFF);
    unsigned short* xbu = (unsigned short*)(ws + XB_OFF);
    unsigned short* pw  = (unsigned short*)(ws + PW_OFF);

    const int use_pw = (ws_size >= (size_t)PW_END) ? 1 : 0;

    if (!use_pw)
        hipMemsetAsync(out, 0, (size_t)NTOK * RD * sizeof(float), stream);
    score_k<<<512, 256, 0, stream>>>(x, rw, sp, xbu);
    topk_k<<<NTOK / 4, 256, 0, stream>>>(sp, out);
    nt_cast<<<2048, 256, 0, stream>>>(nr, nT);
    hist_k<<<NHB, 256, 0, stream>>>(out, gcnt);
    scan_k<<<1, 64, 0, stream>>>(gcnt, boff, cnt);
    scatter_k<<<NHB, 256, 0, stream>>>(out, boff, lists);
    gemm_k<<<NEXP * JMAX, 256, 0, stream>>>(xbu, (const unsigned short*)nT, cnt, lists, out, pw, use_pw);
    if (use_pw)
        reduce_k<<<(NTOK * RD) / 256, 256, 0, stream>>>(pw, out);
}

// Round 10
// 120.216 us; speedup vs baseline: 1.2850x; 1.0191x over previous
//
#include <hip/hip_runtime.h>
#include <hip/hip_bf16.h>
#include <stdint.h>

#define NTOK 8192
#define DIM  1024
#define RD   128
#define NEXP 64
#define TOPK 8
#define MAXT 4096
#define NHB  32    // histogram blocks (256 tokens each)
#define JMAX 16    // gemm j-range (covers 2048 tokens/expert; actual ~1024±150)

// d_out element offsets (f32 elements): output | weights | idx
#define W_OFF (NTOK * RD)            // 1048576
#define I_OFF (W_OFF + NTOK * TOPK)  // 1114112

// ws byte offsets
#define CNT_OFF  0
#define LIST_OFF 1024
#define GC_OFF   (LIST_OFF + NEXP * MAXT * 4)   // 1,049,600
#define BO_OFF   (GC_OFF + NHB * NEXP * 4)      // 1,057,792
#define NT_OFF   2360320
#define XB_OFF   (NT_OFF + (size_t)NEXP * RD * DIM * 2)    // 19,137,536
#define PW_OFF   (XB_OFF + (size_t)NTOK * DIM * 2)         // 35,914,752
#define PW_END   (PW_OFF + (size_t)NTOK * TOPK * RD * 2)   // 52,691,968
// NT region (16 MB) time-shared: sp f64 [4][NTOK][NEXP] during score/topk,
// then nT bf16 (nt_cast runs AFTER topk_k). XB: xb bf16 (fused x_cast).
// PW region (16 MB, bf16 partials) used ONLY if ws_size >= PW_END.

using bh8 = __attribute__((ext_vector_type(8))) short;
using fx4 = __attribute__((ext_vector_type(4))) float;
using dx2 = __attribute__((ext_vector_type(2))) double;
using dx4 = __attribute__((ext_vector_type(4))) double;

__device__ inline unsigned short f2bf(float f) {
    union { __hip_bfloat16 h; unsigned short u; } v;
    v.h = __float2bfloat16(f);
    return v.u;
}

// ---------------------------------------------------------------------------
// Kernel 0: neurons [e][d][r] f32  ->  nT [e][r][d] bf16  (B^T for MFMA)
// ---------------------------------------------------------------------------
__global__ __launch_bounds__(256) void nt_cast(const float* __restrict__ nr,
                                               __hip_bfloat16* __restrict__ nT) {
    int bx  = blockIdx.x;
    int e   = bx >> 5;
    int sub = bx & 31;
    int d0  = (sub >> 1) * 64;
    int r0  = (sub & 1) * 64;
    __shared__ float t[64][65];
    int tid = threadIdx.x;
    int dd  = tid >> 2;
    int rr4 = (tid & 3) * 16;
    const float* src = nr + ((size_t)e * DIM + d0 + dd) * RD + r0 + rr4;
    fx4 v[4];
    #pragma unroll
    for (int u = 0; u < 4; ++u) v[u] = ((const fx4*)src)[u];
    #pragma unroll
    for (int u = 0; u < 4; ++u)
        #pragma unroll
        for (int c = 0; c < 4; ++c) t[dd][rr4 + u * 4 + c] = v[u][c];
    __syncthreads();
    int rr  = tid >> 2;
    int dd4 = (tid & 3) * 16;
    union { unsigned short u[16]; uint4 q[2]; } o;
    #pragma unroll
    for (int i = 0; i < 16; ++i) o.u[i] = f2bf(t[dd4 + i][rr]);
    __hip_bfloat16* dst = nT + ((size_t)e * RD + r0 + rr) * DIM + d0 + dd4;
    ((uint4*)dst)[0] = o.q[0];
    ((uint4*)dst)[1] = o.q[1];
}

// ---------------------------------------------------------------------------
// Kernel 1: fp64 partial router scores, D-split x4 -> sp[ds][T][n]
// v2: LDS tiles staged AS f64 (cvt once at staging, not per-use in the loop),
// reg-prefetch of next chunk issued before the dq-compute (T14),
// token fragment remap ti*4+i (consecutive rows -> 2-way/free LDS reads).
// Per-score d-summation order identical to r9 -> sp bit-identical.
// ALSO emits xb bf16 (fused x_cast).
// ---------------------------------------------------------------------------
__global__ __launch_bounds__(256) void score_k(const float* __restrict__ x,
                                               const float* __restrict__ rw,
                                               double* __restrict__ sp,
                                               unsigned short* __restrict__ xb) {
    __shared__ __align__(16) char smem[2 * 64 * 66 * 8];   // 67,584 B
    double (*Xs)[66] = (double (*)[66])smem;
    double (*Ws)[66] = (double (*)[66])(smem + 64 * 66 * 8);
    double (*Ssc)[65] = (double (*)[65])smem;   // alias after compute (33,280 B)

    int tid = threadIdx.x;
    int ds  = blockIdx.x & 3;
    int tb  = (blockIdx.x >> 2) * 64;
    int ni  = tid & 15;        // experts: ni + 16*j
    int ti  = tid >> 4;        // tokens:  ti*4 + i

    double acc[4][4];
    #pragma unroll
    for (int i = 0; i < 4; ++i)
        #pragma unroll
        for (int j = 0; j < 4; ++j) acc[i][j] = 0.0;

    int srow = tid >> 2;          // 0..63
    int scol = (tid & 3) * 16;    // 0,16,32,48

    fx4 xv[4], wv[4];
    {   // preload chunk 0
        const float* xs = x  + (size_t)(tb + srow) * DIM + ds * 256 + scol;
        const float* ws = rw + (size_t)srow        * DIM + ds * 256 + scol;
        #pragma unroll
        for (int u = 0; u < 4; ++u) { xv[u] = ((const fx4*)xs)[u]; wv[u] = ((const fx4*)ws)[u]; }
    }

    for (int c = 0; c < 4; ++c) {
        __syncthreads();   // prior dq-compute done reading LDS
        // stage as f64 (cvt once per element)
        #pragma unroll
        for (int u = 0; u < 4; ++u) {
            #pragma unroll
            for (int k = 0; k < 4; k += 2) {
                dx2 xd; xd[0] = (double)xv[u][k]; xd[1] = (double)xv[u][k + 1];
                *(dx2*)&Xs[srow][scol + u * 4 + k] = xd;
                dx2 wd; wd[0] = (double)wv[u][k]; wd[1] = (double)wv[u][k + 1];
                *(dx2*)&Ws[srow][scol + u * 4 + k] = wd;
            }
        }
        // fused x_cast (this thread's 16 x-floats)
        {
            bh8 o0, o1;
            #pragma unroll
            for (int c2 = 0; c2 < 4; ++c2) {
                o0[c2]     = (short)f2bf(xv[0][c2]);
                o0[4 + c2] = (short)f2bf(xv[1][c2]);
                o1[c2]     = (short)f2bf(xv[2][c2]);
                o1[4 + c2] = (short)f2bf(xv[3][c2]);
            }
            unsigned short* xd = xb + (size_t)(tb + srow) * DIM + ds * 256 + c * 64 + scol;
            *(bh8*)xd = o0;
            *(bh8*)(xd + 8) = o1;
        }
        __syncthreads();
        if (c < 3) {   // prefetch next chunk; latency hides under dq-compute
            int d0 = ds * 256 + (c + 1) * 64;
            const float* xs = x  + (size_t)(tb + srow) * DIM + d0 + scol;
            const float* ws = rw + (size_t)srow        * DIM + d0 + scol;
            #pragma unroll
            for (int u = 0; u < 4; ++u) { xv[u] = ((const fx4*)xs)[u]; wv[u] = ((const fx4*)ws)[u]; }
        }
        // pure-f64 inner loop
        for (int dq = 0; dq < 64; dq += 4) {
            dx4 xa[4], wb[4];
            #pragma unroll
            for (int i = 0; i < 4; ++i) xa[i] = *(const dx4*)&Xs[ti * 4 + i][dq];
            #pragma unroll
            for (int j = 0; j < 4; ++j) wb[j] = *(const dx4*)&Ws[ni + 16 * j][dq];
            #pragma unroll
            for (int i = 0; i < 4; ++i)
                #pragma unroll
                for (int j = 0; j < 4; ++j)
                    acc[i][j] += xa[i][0] * wb[j][0]
                               + xa[i][1] * wb[j][1]
                               + xa[i][2] * wb[j][2]
                               + xa[i][3] * wb[j][3];
        }
    }
    __syncthreads();   // done reading Xs/Ws; safe to alias with Ssc
    #pragma unroll
    for (int i = 0; i < 4; ++i)
        #pragma unroll
        for (int j = 0; j < 4; ++j) Ssc[ti * 4 + i][ni + 16 * j] = acc[i][j];
    __syncthreads();

    int t  = tid >> 2;
    int n0 = (tid & 3) * 16;
    double* dst = sp + ((size_t)ds * NTOK + tb + t) * NEXP + n0;
    #pragma unroll
    for (int k = 0; k < 16; ++k) dst[k] = Ssc[t][n0 + k];
}

// ---------------------------------------------------------------------------
// Kernel 2: wave-per-token f64 top-8 + softmax. Plain stores only.
// ---------------------------------------------------------------------------
__global__ __launch_bounds__(256) void topk_k(const double* __restrict__ sp,
                                              float* __restrict__ out) {
    int wave = threadIdx.x >> 6, lane = threadIdx.x & 63;
    int T = blockIdx.x * 4 + wave;

    const double* base = sp + (size_t)T * NEXP + lane;
    const size_t SL = (size_t)NTOK * NEXP;
    double s = base[0] + base[SL] + base[2 * SL] + base[3 * SL];

    double vals[TOPK]; int idxs[TOPK];
    double cur = s;
    #pragma unroll
    for (int p = 0; p < TOPK; ++p) {
        double v = cur; int i = lane;
        #pragma unroll
        for (int off = 32; off > 0; off >>= 1) {
            double ov = __shfl_xor(v, off, 64);
            int    oi = __shfl_xor(i, off, 64);
            if (ov > v || (ov == v && oi < i)) { v = ov; i = oi; }
        }
        vals[p] = v; idxs[p] = i;
        if (lane == i) cur = -1e300;
    }

    double m = vals[0], sum = 0.0, ex[TOPK];
    #pragma unroll
    for (int p = 0; p < TOPK; ++p) { ex[p] = exp(vals[p] - m); sum += ex[p]; }
    double inv = 1.0 / sum;

    if (lane < TOPK) {
        int p = lane;
        out[W_OFF + T * TOPK + p] = (float)(ex[p] * inv);
        out[I_OFF + T * TOPK + p] = (float)idxs[p];
    }
}

// ---------------------------------------------------------------------------
// Kernel 3: per-block expert histogram (LDS atomics only)
// ---------------------------------------------------------------------------
__global__ __launch_bounds__(256) void hist_k(const float* __restrict__ out,
                                              int* __restrict__ gcnt) {
    __shared__ int lh[NEXP];
    int tid = threadIdx.x;
    if (tid < NEXP) lh[tid] = 0;
    __syncthreads();
    int T = blockIdx.x * 256 + tid;
    const fx4* ip = (const fx4*)(out + I_OFF + (size_t)T * TOPK);
    fx4 a = ip[0], b = ip[1];
    #pragma unroll
    for (int p = 0; p < 4; ++p) { atomicAdd(&lh[(int)a[p]], 1); atomicAdd(&lh[(int)b[p]], 1); }
    __syncthreads();
    if (tid < NEXP) gcnt[blockIdx.x * NEXP + tid] = lh[tid];
}

// ---------------------------------------------------------------------------
// Kernel 4: scan block counts -> per-block bases + total cnt
// ---------------------------------------------------------------------------
__global__ __launch_bounds__(64) void scan_k(const int* __restrict__ gcnt,
                                             int* __restrict__ boff,
                                             int* __restrict__ cnt) {
    int e = threadIdx.x;
    int s = 0;
    #pragma unroll
    for (int b = 0; b < NHB; ++b) {
        boff[b * NEXP + e] = e * MAXT + s;
        s += gcnt[b * NEXP + e];
    }
    cnt[e] = s;
}

// ---------------------------------------------------------------------------
// Kernel 5: scatter entries into lists (LDS-atomic local ranks)
// ---------------------------------------------------------------------------
__global__ __launch_bounds__(256) void scatter_k(const float* __restrict__ out,
                                                 const int* __restrict__ boff,
                                                 int* __restrict__ lists) {
    __shared__ int lh[NEXP];
    __shared__ int bo[NEXP];
    int tid = threadIdx.x;
    if (tid < NEXP) { lh[tid] = 0; bo[tid] = boff[blockIdx.x * NEXP + tid]; }
    __syncthreads();
    int T = blockIdx.x * 256 + tid;
    const fx4* ip = (const fx4*)(out + I_OFF + (size_t)T * TOPK);
    fx4 a = ip[0], b = ip[1];
    int ev[TOPK] = {(int)a[0], (int)a[1], (int)a[2], (int)a[3],
                    (int)b[0], (int)b[1], (int)b[2], (int)b[3]};
    #pragma unroll
    for (int p = 0; p < TOPK; ++p) {
        int e = ev[p];
        int pos = atomicAdd(&lh[e], 1);
        lists[bo[e] + pos] = (T << 3) | p;
    }
}

// ---------------------------------------------------------------------------
// Kernel 6: grouped gather-GEMM, 128 tok x 128 R, BK=64, depth-2 counted-vmcnt
// pipeline (r7 structure). Epilogue: if use_pw, plain bf16 stores of weighted
// partials to pw[p][r] (no atomics); else f32 atomicAdd into out.
// ---------------------------------------------------------------------------
__global__ __launch_bounds__(256) void gemm_k(const unsigned short* __restrict__ xb,
                                              const unsigned short* __restrict__ nTb,
                                              const int* __restrict__ cnt,
                                              const int* __restrict__ lists,
                                              float* __restrict__ outf,
                                              unsigned short* __restrict__ pw,
                                              int use_pw) {
    int e = blockIdx.x & 63;
    int j = blockIdx.x >> 6;
    int ce = cnt[e];
    int base = j * 128;
    if (base >= ce) return;

    __shared__ unsigned short As[2][128 * 64];
    __shared__ unsigned short Bs[2][128 * 64];
    __shared__ int   plist[128];
    __shared__ float wl[128];

    int tid = threadIdx.x;
    int wave = tid >> 6, lane = tid & 63;
    if (tid < 128) {
        int idx = base + tid;
        int p = (idx < ce) ? lists[e * MAXT + idx] : -1;
        plist[tid] = p;
        wl[tid] = (p >= 0) ? outf[W_OFF + p] : 0.0f;
    }
    __syncthreads();

    fx4 acc[4][4];
    #pragma unroll
    for (int a = 0; a < 4; ++a)
        #pragma unroll
        for (int b = 0; b < 4; ++b) acc[a][b] = (fx4){0.f, 0.f, 0.f, 0.f};

    unsigned soff = 16u * (unsigned)((lane & 7) ^ (lane >> 3));
    const char* asrc[4];
    const char* bsrc[4];
    const char* xbb = (const char*)xb;
    const char* ntb = (const char*)(nTb + (size_t)e * RD * DIM);
    #pragma unroll
    for (int c = 0; c < 4; ++c) {
        int row = (wave * 4 + c) * 8 + (lane >> 3);
        int p = plist[row];
        int tok = (p < 0) ? 0 : (p >> 3);
        asrc[c] = xbb + (size_t)tok * (DIM * 2) + soff;
        bsrc[c] = ntb + (size_t)row * (DIM * 2) + soff;
    }

    int wm = (wave >> 1) * 64, wn = (wave & 1) * 64;
    int lr = lane & 15, lk = (lane >> 4) * 8;
    int lg = lane >> 4;

    auto stage = [&](int kt, int bsel) {
        int db = kt * 128;
        #pragma unroll
        for (int c = 0; c < 4; ++c) {
            __builtin_amdgcn_global_load_lds(
                (const __attribute__((address_space(1))) void*)(asrc[c] + db),
                (__attribute__((address_space(3))) void*)(&As[bsel][(wave * 4 + c) * 512]),
                16, 0, 0);
        }
        #pragma unroll
        for (int c = 0; c < 4; ++c) {
            __builtin_amdgcn_global_load_lds(
                (const __attribute__((address_space(1))) void*)(bsrc[c] + db),
                (__attribute__((address_space(3))) void*)(&Bs[bsel][(wave * 4 + c) * 512]),
                16, 0, 0);
        }
    };

    auto mfma_tile = [&](int bsel) {
        const char* Ab = (const char*)As[bsel];
        const char* Bb = (const char*)Bs[bsel];
        #pragma unroll
        for (int kk = 0; kk < 2; ++kk) {
            int k0 = kk * 32;
            bh8 av[4], bv[4];
            #pragma unroll
            for (int mf = 0; mf < 4; ++mf) {
                unsigned row = (unsigned)(wm + mf * 16 + lr);
                unsigned bo = row * 128 + (unsigned)(k0 + lk) * 2;
                bo ^= (row & 7) << 4;
                av[mf] = *(const bh8*)(Ab + bo);
            }
            #pragma unroll
            for (int nf = 0; nf < 4; ++nf) {
                unsigned row = (unsigned)(wn + nf * 16 + lr);
                unsigned bo = row * 128 + (unsigned)(k0 + lk) * 2;
                bo ^= (row & 7) << 4;
                bv[nf] = *(const bh8*)(Bb + bo);
            }
            #pragma unroll
            for (int mf = 0; mf < 4; ++mf)
                #pragma unroll
                for (int nf = 0; nf < 4; ++nf)
                    acc[mf][nf] = __builtin_amdgcn_mfma_f32_16x16x32_bf16(av[mf], bv[nf], acc[mf][nf], 0, 0, 0);
        }
    };

    stage(0, 0);
    stage(1, 1);

    for (int kt = 0; kt < 15; ++kt) {
        int bsel = kt & 1;
        asm volatile("s_waitcnt vmcnt(8)" ::: "memory");
        __builtin_amdgcn_s_barrier();
        asm volatile("" ::: "memory");
        mfma_tile(bsel);
        asm volatile("s_waitcnt lgkmcnt(0)" ::: "memory");
        __builtin_amdgcn_s_barrier();
        asm volatile("" ::: "memory");
        if (kt < 14) stage(kt + 2, bsel);
    }
    asm volatile("s_waitcnt vmcnt(0)" ::: "memory");
    __builtin_amdgcn_s_barrier();
    asm volatile("" ::: "memory");
    mfma_tile(1);

    if (use_pw) {
        #pragma unroll
        for (int mf = 0; mf < 4; ++mf) {
            #pragma unroll
            for (int rg = 0; rg < 4; ++rg) {
                int row = wm + mf * 16 + lg * 4 + rg;
                int p = plist[row];
                if (p < 0) continue;
                float wg = wl[row];
                #pragma unroll
                for (int nf = 0; nf < 4; ++nf) {
                    int r = wn + nf * 16 + lr;
                    pw[(size_t)p * RD + r] = f2bf(acc[mf][nf][rg] * wg);
                }
            }
        }
    } else {
        #pragma unroll
        for (int mf = 0; mf < 4; ++mf) {
            #pragma unroll
            for (int rg = 0; rg < 4; ++rg) {
                int row = wm + mf * 16 + lg * 4 + rg;
                int p = plist[row];
                if (p < 0) continue;
                float wg = wl[row];
                int t = p >> 3;
                #pragma unroll
                for (int nf = 0; nf < 4; ++nf) {
                    int r = wn + nf * 16 + lr;
                    atomicAdd(&outf[(size_t)t * RD + r], acc[mf][nf][rg] * wg);
                }
            }
        }
    }
}

// ---------------------------------------------------------------------------
// Kernel 7: y[t][r] = sum_k pw[(t*8+k)][r]   (pw path only; coalesced)
// ---------------------------------------------------------------------------
__global__ __launch_bounds__(256) void reduce_k(const unsigned short* __restrict__ pw,
                                                float* __restrict__ y) {
    int gid = blockIdx.x * 256 + threadIdx.x;
    int t = gid >> 7, r = gid & 127;
    float s = 0.f;
    #pragma unroll
    for (int k = 0; k < TOPK; ++k) {
        unsigned int w = ((unsigned int)pw[((size_t)t * TOPK + k) * RD + r]) << 16;
        s += __uint_as_float(w);
    }
    y[gid] = s;
}

// ---------------------------------------------------------------------------
extern "C" void kernel_launch(void* const* d_in, const int* in_sizes, int n_in,
                              void* d_out, int out_size, void* d_ws, size_t ws_size,
                              hipStream_t stream) {
    const float* x  = (const float*)d_in[0];
    const float* rw = (const float*)d_in[1];
    const float* nr = (const float*)d_in[2];
    float* out = (float*)d_out;
    char* ws = (char*)d_ws;
    int*    cnt   = (int*)(ws + CNT_OFF);
    int*    lists = (int*)(ws + LIST_OFF);
    int*    gcnt  = (int*)(ws + GC_OFF);
    int*    boff  = (int*)(ws + BO_OFF);
    __hip_bfloat16* nT = (__hip_bfloat16*)(ws + NT_OFF);
    double* sp    = (double*)(ws + NT_OFF);
    unsigned short* xbu = (unsigned short*)(ws + XB_OFF);
    unsigned short* pw  = (unsigned short*)(ws + PW_OFF);

    const int use_pw = (ws_size >= (size_t)PW_END) ? 1 : 0;

    if (!use_pw)
        hipMemsetAsync(out, 0, (size_t)NTOK * RD * sizeof(float), stream);
    score_k<<<512, 256, 0, stream>>>(x, rw, sp, xbu);
    topk_k<<<NTOK / 4, 256, 0, stream>>>(sp, out);
    nt_cast<<<2048, 256, 0, stream>>>(nr, nT);
    hist_k<<<NHB, 256, 0, stream>>>(out, gcnt);
    scan_k<<<1, 64, 0, stream>>>(gcnt, boff, cnt);
    scatter_k<<<NHB, 256, 0, stream>>>(out, boff, lists);
    gemm_k<<<NEXP * JMAX, 256, 0, stream>>>(xbu, (const unsigned short*)nT, cnt, lists, out, pw, use_pw);
    if (use_pw)
        reduce_k<<<(NTOK * RD) / 256, 256, 0, stream>>>(pw, out);
}

// Round 12
// 112.795 us; speedup vs baseline: 1.3696x; 1.0658x over previous
//
#include <hip/hip_runtime.h>
#include <hip/hip_bf16.h>
#include <stdint.h>

#define NTOK 8192
#define DIM  1024
#define RD   128
#define NEXP 64
#define TOPK 8
#define MAXT 4096
#define NHB  32    // histogram blocks (256 tokens each)
#define JM   32    // gemm j-range at M=64 (covers 2048 tokens/expert)

// d_out element offsets (f32 elements): output | weights | idx
#define W_OFF (NTOK * RD)            // 1048576
#define I_OFF (W_OFF + NTOK * TOPK)  // 1114112

// ws byte offsets
#define CNT_OFF  0
#define LIST_OFF 1024
#define GC_OFF   (LIST_OFF + NEXP * MAXT * 4)   // 1,049,600
#define BO_OFF   (GC_OFF + NHB * NEXP * 4)      // 1,057,792
#define NT_OFF   2360320
#define XB_OFF   (NT_OFF + (size_t)NEXP * RD * DIM * 2)    // 19,137,536
#define PW_OFF   (XB_OFF + (size_t)NTOK * DIM * 2)         // 35,914,752
#define PW_END   (PW_OFF + (size_t)NTOK * TOPK * RD * 2)   // 52,691,968
// NT region (16 MB) time-shared: sp f64 [4][NTOK][NEXP] during score/topk,
// then nT bf16 (nt_cast runs AFTER topk_k). XB: xb bf16 (fused x_cast).
// PW region (16 MB, bf16 partials) used ONLY if ws_size >= PW_END.

using bh8 = __attribute__((ext_vector_type(8))) short;
using fx4 = __attribute__((ext_vector_type(4))) float;
using dx2 = __attribute__((ext_vector_type(2))) double;
using dx4 = __attribute__((ext_vector_type(4))) double;

__device__ inline unsigned short f2bf(float f) {
    union { __hip_bfloat16 h; unsigned short u; } v;
    v.h = __float2bfloat16(f);
    return v.u;
}

// ---------------------------------------------------------------------------
// Kernel 0: neurons [e][d][r] f32  ->  nT [e][r][d] bf16  (B^T for MFMA)
// ---------------------------------------------------------------------------
__global__ __launch_bounds__(256) void nt_cast(const float* __restrict__ nr,
                                               __hip_bfloat16* __restrict__ nT) {
    int bx  = blockIdx.x;
    int e   = bx >> 5;
    int sub = bx & 31;
    int d0  = (sub >> 1) * 64;
    int r0  = (sub & 1) * 64;
    __shared__ float t[64][65];
    int tid = threadIdx.x;
    int dd  = tid >> 2;
    int rr4 = (tid & 3) * 16;
    const float* src = nr + ((size_t)e * DIM + d0 + dd) * RD + r0 + rr4;
    fx4 v[4];
    #pragma unroll
    for (int u = 0; u < 4; ++u) v[u] = ((const fx4*)src)[u];
    #pragma unroll
    for (int u = 0; u < 4; ++u)
        #pragma unroll
        for (int c = 0; c < 4; ++c) t[dd][rr4 + u * 4 + c] = v[u][c];
    __syncthreads();
    int rr  = tid >> 2;
    int dd4 = (tid & 3) * 16;
    union { unsigned short u[16]; uint4 q[2]; } o;
    #pragma unroll
    for (int i = 0; i < 16; ++i) o.u[i] = f2bf(t[dd4 + i][rr]);
    __hip_bfloat16* dst = nT + ((size_t)e * RD + r0 + rr) * DIM + d0 + dd4;
    ((uint4*)dst)[0] = o.q[0];
    ((uint4*)dst)[1] = o.q[1];
}

// ---------------------------------------------------------------------------
// Kernel 1: fp64 partial router scores, D-split x4 -> sp[ds][T][n]
// (r10-proven version: f64 LDS tiles, reg-prefetch, fused x_cast)
// ---------------------------------------------------------------------------
__global__ __launch_bounds__(256) void score_k(const float* __restrict__ x,
                                               const float* __restrict__ rw,
                                               double* __restrict__ sp,
                                               unsigned short* __restrict__ xb) {
    __shared__ __align__(16) char smem[2 * 64 * 66 * 8];   // 67,584 B
    double (*Xs)[66] = (double (*)[66])smem;
    double (*Ws)[66] = (double (*)[66])(smem + 64 * 66 * 8);
    double (*Ssc)[65] = (double (*)[65])smem;   // alias after compute

    int tid = threadIdx.x;
    int ds  = blockIdx.x & 3;
    int tb  = (blockIdx.x >> 2) * 64;
    int ni  = tid & 15;        // experts: ni + 16*j
    int ti  = tid >> 4;        // tokens:  ti*4 + i

    double acc[4][4];
    #pragma unroll
    for (int i = 0; i < 4; ++i)
        #pragma unroll
        for (int j = 0; j < 4; ++j) acc[i][j] = 0.0;

    int srow = tid >> 2;          // 0..63
    int scol = (tid & 3) * 16;    // 0,16,32,48

    fx4 xv[4], wv[4];
    {   // preload chunk 0
        const float* xs = x  + (size_t)(tb + srow) * DIM + ds * 256 + scol;
        const float* ws = rw + (size_t)srow        * DIM + ds * 256 + scol;
        #pragma unroll
        for (int u = 0; u < 4; ++u) { xv[u] = ((const fx4*)xs)[u]; wv[u] = ((const fx4*)ws)[u]; }
    }

    for (int c = 0; c < 4; ++c) {
        __syncthreads();   // prior dq-compute done reading LDS
        #pragma unroll
        for (int u = 0; u < 4; ++u) {
            #pragma unroll
            for (int k = 0; k < 4; k += 2) {
                dx2 xd; xd[0] = (double)xv[u][k]; xd[1] = (double)xv[u][k + 1];
                *(dx2*)&Xs[srow][scol + u * 4 + k] = xd;
                dx2 wd; wd[0] = (double)wv[u][k]; wd[1] = (double)wv[u][k + 1];
                *(dx2*)&Ws[srow][scol + u * 4 + k] = wd;
            }
        }
        // fused x_cast
        {
            bh8 o0, o1;
            #pragma unroll
            for (int c2 = 0; c2 < 4; ++c2) {
                o0[c2]     = (short)f2bf(xv[0][c2]);
                o0[4 + c2] = (short)f2bf(xv[1][c2]);
                o1[c2]     = (short)f2bf(xv[2][c2]);
                o1[4 + c2] = (short)f2bf(xv[3][c2]);
            }
            unsigned short* xd = xb + (size_t)(tb + srow) * DIM + ds * 256 + c * 64 + scol;
            *(bh8*)xd = o0;
            *(bh8*)(xd + 8) = o1;
        }
        __syncthreads();
        if (c < 3) {   // prefetch next chunk
            int d0 = ds * 256 + (c + 1) * 64;
            const float* xs = x  + (size_t)(tb + srow) * DIM + d0 + scol;
            const float* ws = rw + (size_t)srow        * DIM + d0 + scol;
            #pragma unroll
            for (int u = 0; u < 4; ++u) { xv[u] = ((const fx4*)xs)[u]; wv[u] = ((const fx4*)ws)[u]; }
        }
        for (int dq = 0; dq < 64; dq += 4) {
            dx4 xa[4], wb[4];
            #pragma unroll
            for (int i = 0; i < 4; ++i) xa[i] = *(const dx4*)&Xs[ti * 4 + i][dq];
            #pragma unroll
            for (int j = 0; j < 4; ++j) wb[j] = *(const dx4*)&Ws[ni + 16 * j][dq];
            #pragma unroll
            for (int i = 0; i < 4; ++i)
                #pragma unroll
                for (int j = 0; j < 4; ++j)
                    acc[i][j] += xa[i][0] * wb[j][0]
                               + xa[i][1] * wb[j][1]
                               + xa[i][2] * wb[j][2]
                               + xa[i][3] * wb[j][3];
        }
    }
    __syncthreads();
    #pragma unroll
    for (int i = 0; i < 4; ++i)
        #pragma unroll
        for (int j = 0; j < 4; ++j) Ssc[ti * 4 + i][ni + 16 * j] = acc[i][j];
    __syncthreads();

    int t  = tid >> 2;
    int n0 = (tid & 3) * 16;
    double* dst = sp + ((size_t)ds * NTOK + tb + t) * NEXP + n0;
    #pragma unroll
    for (int k = 0; k < 16; ++k) dst[k] = Ssc[t][n0 + k];
}

// ---------------------------------------------------------------------------
// Kernel 2: wave-per-token f64 top-8 + softmax. Plain stores only.
// ---------------------------------------------------------------------------
__global__ __launch_bounds__(256) void topk_k(const double* __restrict__ sp,
                                              float* __restrict__ out) {
    int wave = threadIdx.x >> 6, lane = threadIdx.x & 63;
    int T = blockIdx.x * 4 + wave;

    const double* base = sp + (size_t)T * NEXP + lane;
    const size_t SL = (size_t)NTOK * NEXP;
    double s = base[0] + base[SL] + base[2 * SL] + base[3 * SL];

    double vals[TOPK]; int idxs[TOPK];
    double cur = s;
    #pragma unroll
    for (int p = 0; p < TOPK; ++p) {
        double v = cur; int i = lane;
        #pragma unroll
        for (int off = 32; off > 0; off >>= 1) {
            double ov = __shfl_xor(v, off, 64);
            int    oi = __shfl_xor(i, off, 64);
            if (ov > v || (ov == v && oi < i)) { v = ov; i = oi; }
        }
        vals[p] = v; idxs[p] = i;
        if (lane == i) cur = -1e300;
    }

    double m = vals[0], sum = 0.0, ex[TOPK];
    #pragma unroll
    for (int p = 0; p < TOPK; ++p) { ex[p] = exp(vals[p] - m); sum += ex[p]; }
    double inv = 1.0 / sum;

    if (lane < TOPK) {
        int p = lane;
        out[W_OFF + T * TOPK + p] = (float)(ex[p] * inv);
        out[I_OFF + T * TOPK + p] = (float)idxs[p];
    }
}

// ---------------------------------------------------------------------------
// Kernel 3: per-block expert histogram (LDS atomics only)
// ---------------------------------------------------------------------------
__global__ __launch_bounds__(256) void hist_k(const float* __restrict__ out,
                                              int* __restrict__ gcnt) {
    __shared__ int lh[NEXP];
    int tid = threadIdx.x;
    if (tid < NEXP) lh[tid] = 0;
    __syncthreads();
    int T = blockIdx.x * 256 + tid;
    const fx4* ip = (const fx4*)(out + I_OFF + (size_t)T * TOPK);
    fx4 a = ip[0], b = ip[1];
    #pragma unroll
    for (int p = 0; p < 4; ++p) { atomicAdd(&lh[(int)a[p]], 1); atomicAdd(&lh[(int)b[p]], 1); }
    __syncthreads();
    if (tid < NEXP) gcnt[blockIdx.x * NEXP + tid] = lh[tid];
}

// ---------------------------------------------------------------------------
// Kernel 4: scan block counts -> per-block bases + total cnt
// ---------------------------------------------------------------------------
__global__ __launch_bounds__(64) void scan_k(const int* __restrict__ gcnt,
                                             int* __restrict__ boff,
                                             int* __restrict__ cnt) {
    int e = threadIdx.x;
    int s = 0;
    #pragma unroll
    for (int b = 0; b < NHB; ++b) {
        boff[b * NEXP + e] = e * MAXT + s;
        s += gcnt[b * NEXP + e];
    }
    cnt[e] = s;
}

// ---------------------------------------------------------------------------
// Kernel 5: scatter entries into lists (LDS-atomic local ranks)
// ---------------------------------------------------------------------------
__global__ __launch_bounds__(256) void scatter_k(const float* __restrict__ out,
                                                 const int* __restrict__ boff,
                                                 int* __restrict__ lists) {
    __shared__ int lh[NEXP];
    __shared__ int bo[NEXP];
    int tid = threadIdx.x;
    if (tid < NEXP) { lh[tid] = 0; bo[tid] = boff[blockIdx.x * NEXP + tid]; }
    __syncthreads();
    int T = blockIdx.x * 256 + tid;
    const fx4* ip = (const fx4*)(out + I_OFF + (size_t)T * TOPK);
    fx4 a = ip[0], b = ip[1];
    int ev[TOPK] = {(int)a[0], (int)a[1], (int)a[2], (int)a[3],
                    (int)b[0], (int)b[1], (int)b[2], (int)b[3]};
    #pragma unroll
    for (int p = 0; p < TOPK; ++p) {
        int e = ev[p];
        int pos = atomicAdd(&lh[e], 1);
        lists[bo[e] + pos] = (T << 3) | p;
    }
}

// ---------------------------------------------------------------------------
// Kernel 6: grouped gather-GEMM, tile 64 tok x 128 R, BK=64, depth-2
// counted-vmcnt pipeline. M=64 (was 128): LDS 48.5 KB -> 3 blocks/CU (was 2),
// 2x active blocks -> better gather-latency cover. 6 loads/lane/step ->
// steady wait vmcnt(6). Epilogue: pw bf16 stores or f32 atomicAdd.
// ---------------------------------------------------------------------------
__global__ __launch_bounds__(256) void gemm_k(const unsigned short* __restrict__ xb,
                                              const unsigned short* __restrict__ nTb,
                                              const int* __restrict__ cnt,
                                              const int* __restrict__ lists,
                                              float* __restrict__ outf,
                                              unsigned short* __restrict__ pw,
                                              int use_pw) {
    int e = blockIdx.x & 63;
    int j = blockIdx.x >> 6;       // 0..JM-1
    int ce = cnt[e];
    int base = j * 64;
    if (base >= ce) return;

    __shared__ unsigned short As[2][64 * 64];    // 16 KB
    __shared__ unsigned short Bs[2][128 * 64];   // 32 KB
    __shared__ int   plist[64];
    __shared__ float wl[64];

    int tid = threadIdx.x;
    int wave = tid >> 6, lane = tid & 63;
    if (tid < 64) {
        int idx = base + tid;
        int p = (idx < ce) ? lists[e * MAXT + idx] : -1;
        plist[tid] = p;
        wl[tid] = (p >= 0) ? outf[W_OFF + p] : 0.0f;
    }
    __syncthreads();

    fx4 acc[2][4];
    #pragma unroll
    for (int a = 0; a < 2; ++a)
        #pragma unroll
        for (int b = 0; b < 4; ++b) acc[a][b] = (fx4){0.f, 0.f, 0.f, 0.f};

    unsigned soff = 16u * (unsigned)((lane & 7) ^ (lane >> 3));
    const char* asrc[2];
    const char* bsrc[4];
    const char* xbb = (const char*)xb;
    const char* ntb = (const char*)(nTb + (size_t)e * RD * DIM);
    #pragma unroll
    for (int c = 0; c < 2; ++c) {
        int row = (wave * 2 + c) * 8 + (lane >> 3);   // 0..63
        int p = plist[row];
        int tok = (p < 0) ? 0 : (p >> 3);
        asrc[c] = xbb + (size_t)tok * (DIM * 2) + soff;
    }
    #pragma unroll
    for (int c = 0; c < 4; ++c) {
        int row = (wave * 4 + c) * 8 + (lane >> 3);   // 0..127
        bsrc[c] = ntb + (size_t)row * (DIM * 2) + soff;
    }

    int wm = (wave >> 1) * 32, wn = (wave & 1) * 64;
    int lr = lane & 15, lk = (lane >> 4) * 8;
    int lg = lane >> 4;

    auto stage = [&](int kt, int bsel) {
        int db = kt * 128;
        #pragma unroll
        for (int c = 0; c < 2; ++c) {
            __builtin_amdgcn_global_load_lds(
                (const __attribute__((address_space(1))) void*)(asrc[c] + db),
                (__attribute__((address_space(3))) void*)(&As[bsel][(wave * 2 + c) * 512]),
                16, 0, 0);
        }
        #pragma unroll
        for (int c = 0; c < 4; ++c) {
            __builtin_amdgcn_global_load_lds(
                (const __attribute__((address_space(1))) void*)(bsrc[c] + db),
                (__attribute__((address_space(3))) void*)(&Bs[bsel][(wave * 4 + c) * 512]),
                16, 0, 0);
        }
    };

    auto mfma_tile = [&](int bsel) {
        const char* Ab = (const char*)As[bsel];
        const char* Bb = (const char*)Bs[bsel];
        #pragma unroll
        for (int kk = 0; kk < 2; ++kk) {
            int k0 = kk * 32;
            bh8 av[2], bv[4];
            #pragma unroll
            for (int mf = 0; mf < 2; ++mf) {
                unsigned row = (unsigned)(wm + mf * 16 + lr);
                unsigned bo = row * 128 + (unsigned)(k0 + lk) * 2;
                bo ^= (row & 7) << 4;
                av[mf] = *(const bh8*)(Ab + bo);
            }
            #pragma unroll
            for (int nf = 0; nf < 4; ++nf) {
                unsigned row = (unsigned)(wn + nf * 16 + lr);
                unsigned bo = row * 128 + (unsigned)(k0 + lk) * 2;
                bo ^= (row & 7) << 4;
                bv[nf] = *(const bh8*)(Bb + bo);
            }
            #pragma unroll
            for (int mf = 0; mf < 2; ++mf)
                #pragma unroll
                for (int nf = 0; nf < 4; ++nf)
                    acc[mf][nf] = __builtin_amdgcn_mfma_f32_16x16x32_bf16(av[mf], bv[nf], acc[mf][nf], 0, 0, 0);
        }
    };

    // prologue: 2 tiles in flight (12 loads/lane)
    stage(0, 0);
    stage(1, 1);

    for (int kt = 0; kt < 15; ++kt) {
        int bsel = kt & 1;
        // wait this tile's 6 loads; next tile's 6 stay in flight
        asm volatile("s_waitcnt vmcnt(6)" ::: "memory");
        __builtin_amdgcn_s_barrier();
        asm volatile("" ::: "memory");
        mfma_tile(bsel);
        asm volatile("s_waitcnt lgkmcnt(0)" ::: "memory");
        __builtin_amdgcn_s_barrier();
        asm volatile("" ::: "memory");
        if (kt < 14) stage(kt + 2, bsel);
    }
    asm volatile("s_waitcnt vmcnt(0)" ::: "memory");
    __builtin_amdgcn_s_barrier();
    asm volatile("" ::: "memory");
    mfma_tile(1);

    if (use_pw) {
        #pragma unroll
        for (int mf = 0; mf < 2; ++mf) {
            #pragma unroll
            for (int rg = 0; rg < 4; ++rg) {
                int row = wm + mf * 16 + lg * 4 + rg;
                int p = plist[row];
                if (p < 0) continue;
                float wg = wl[row];
                #pragma unroll
                for (int nf = 0; nf < 4; ++nf) {
                    int r = wn + nf * 16 + lr;
                    pw[(size_t)p * RD + r] = f2bf(acc[mf][nf][rg] * wg);
                }
            }
        }
    } else {
        #pragma unroll
        for (int mf = 0; mf < 2; ++mf) {
            #pragma unroll
            for (int rg = 0; rg < 4; ++rg) {
                int row = wm + mf * 16 + lg * 4 + rg;
                int p = plist[row];
                if (p < 0) continue;
                float wg = wl[row];
                int t = p >> 3;
                #pragma unroll
                for (int nf = 0; nf < 4; ++nf) {
                    int r = wn + nf * 16 + lr;
                    atomicAdd(&outf[(size_t)t * RD + r], acc[mf][nf][rg] * wg);
                }
            }
        }
    }
}

// ---------------------------------------------------------------------------
// Kernel 7: y[t][r] = sum_k pw[(t*8+k)][r]   (pw path only; coalesced)
// ---------------------------------------------------------------------------
__global__ __launch_bounds__(256) void reduce_k(const unsigned short* __restrict__ pw,
                                                float* __restrict__ y) {
    int gid = blockIdx.x * 256 + threadIdx.x;
    int t = gid >> 7, r = gid & 127;
    float s = 0.f;
    #pragma unroll
    for (int k = 0; k < TOPK; ++k) {
        unsigned int w = ((unsigned int)pw[((size_t)t * TOPK + k) * RD + r]) << 16;
        s += __uint_as_float(w);
    }
    y[gid] = s;
}

// ---------------------------------------------------------------------------
extern "C" void kernel_launch(void* const* d_in, const int* in_sizes, int n_in,
                              void* d_out, int out_size, void* d_ws, size_t ws_size,
                              hipStream_t stream) {
    const float* x  = (const float*)d_in[0];
    const float* rw = (const float*)d_in[1];
    const float* nr = (const float*)d_in[2];
    float* out = (float*)d_out;
    char* ws = (char*)d_ws;
    int*    cnt   = (int*)(ws + CNT_OFF);
    int*    lists = (int*)(ws + LIST_OFF);
    int*    gcnt  = (int*)(ws + GC_OFF);
    int*    boff  = (int*)(ws + BO_OFF);
    __hip_bfloat16* nT = (__hip_bfloat16*)(ws + NT_OFF);
    double* sp    = (double*)(ws + NT_OFF);
    unsigned short* xbu = (unsigned short*)(ws + XB_OFF);
    unsigned short* pw  = (unsigned short*)(ws + PW_OFF);

    const int use_pw = (ws_size >= (size_t)PW_END) ? 1 : 0;

    if (!use_pw)
        hipMemsetAsync(out, 0, (size_t)NTOK * RD * sizeof(float), stream);
    score_k<<<512, 256, 0, stream>>>(x, rw, sp, xbu);
    topk_k<<<NTOK / 4, 256, 0, stream>>>(sp, out);
    nt_cast<<<2048, 256, 0, stream>>>(nr, nT);
    hist_k<<<NHB, 256, 0, stream>>>(out, gcnt);
    scan_k<<<1, 64, 0, stream>>>(gcnt, boff, cnt);
    scatter_k<<<NHB, 256, 0, stream>>>(out, boff, lists);
    gemm_k<<<NEXP * JM, 256, 0, stream>>>(xbu, (const unsigned short*)nT, cnt, lists, out, pw, use_pw);
    if (use_pw)
        reduce_k<<<(NTOK * RD) / 256, 256, 0, stream>>>(pw, out);
}